// Round 15
// baseline (142.285 us; speedup 1.0000x reference)
//
#include <hip/hip_runtime.h>
#include <hip/hip_bf16.h>

#define N 8192
#define D 128
#define LOG2E  1.44269504088896f
#define LN2    0.69314718055995f
#define NPLANE 64

typedef __attribute__((ext_vector_type(8))) short bf16x8;
typedef __attribute__((ext_vector_type(4))) float f32x4;

#if __has_builtin(__builtin_amdgcn_exp2f)
#define EXP2(x) __builtin_amdgcn_exp2f(x)
#else
#define EXP2(x) exp2f(x)
#endif
#if __has_builtin(__builtin_amdgcn_logf)
#define LOG2(x) __builtin_amdgcn_logf(x)
#else
#define LOG2(x) log2f(x)
#endif

union FragU { unsigned int u[4]; bf16x8 v; };

static __device__ __forceinline__ unsigned int pk2(float x, float y) {
    __hip_bfloat162 h = __float22bfloat162_rn(float2{x, y});
    return *reinterpret_cast<unsigned int*>(&h);
}

// Load one MFMA bf16 fragment for this lane straight from fp32 row-major E.
// row = row0 + l ; cols kk*32 + q*8 .. +7. Lanes(q,l) cover 128B/row
// contiguously across q -> per 1-KB wave-instr = 8 full 128-B lines (ideal).
static __device__ __forceinline__ bf16x8 load_frag(
        const float* __restrict__ E, int row, int kk, int q) {
    const float* p = E + (size_t)row * D + kk * 32 + q * 8;
    float4 f0 = *(const float4*)p;
    float4 f1 = *(const float4*)(p + 4);
    FragU f;
    f.u[0] = pk2(f0.x, f0.y);
    f.u[1] = pk2(f0.z, f0.w);
    f.u[2] = pk2(f1.x, f1.y);
    f.u[3] = pk2(f1.z, f1.w);
    return f.v;
}

// Kernel 1 (R15): fused, reading fp32 E DIRECTLY (no prep kernel, no Eb2).
// R14 post-mortem: per-block amortization neutral -> everything inside the
// kernel is exonerated (work volume R7, barriers R8, atomics R9, coalescing
// R10/11, prefetch R12, tile shape R14). Remaining structural suspects are
// cross-kernel: prep launch + gap + end-of-kernel L2 flush serialization.
// This round: in-register fp32->bf16 conversion per fragment (packed cvt),
// E (4 MB) is per-XCD-L2 resident; coalescing ideal (see load_frag).
// +~1.5K VALU cyc/block — free if the idle theory holds; if it regresses,
// that's decisive evidence fused is issue-bound (then optimize exp chain).
// Kept: R11 triangular 128x128 geometry, plane stores/no global atomics
// (R9), rolled loops (R4), no min-waves bound (R2), tiny epilogue (R3).
__global__ __launch_bounds__(256) void fused_kernel(
        const float* __restrict__ E,
        const int* __restrict__ labels,
        float* __restrict__ part,
        unsigned int* __restrict__ counter) {
    __shared__ int   labC[128];
    __shared__ int   labR[128];
    __shared__ float colacc[128];

    const int tid  = threadIdx.x;
    const int wid  = tid >> 6;     // 0..3
    const int lane = tid & 63;
    const int q = lane >> 4;       // 0..3
    const int l = lane & 15;       // 0..15

    if (blockIdx.x == 0 && tid == 0) *counter = 0u;  // for finalize ticket

    // Triangular tile decode b -> (r, c), r <= c, 64 row-tiles (128 wide).
    const int b = blockIdx.x;
    int r = (int)(64.5f - sqrtf(64.5f * 64.5f - 2.0f * (float)b));
    while ((r + 1) * 64 - ((r + 1) * r) / 2 <= b) ++r;
    while (r * 64 - (r * (r - 1)) / 2 > b) --r;
    const int c = r + (b - (r * 64 - (r * (r - 1)) / 2));
    const bool diag = (r == c);
    const int tile_m0 = r * 128;
    const int n_begin = c * 128;
    const int mrow0 = wid * 32;            // wave's row strip within tile

    // A fragments: convert in-register from fp32 E.
    bf16x8 a[2][4];
#pragma unroll
    for (int g = 0; g < 2; ++g)
#pragma unroll
        for (int kk = 0; kk < 4; ++kk)
            a[g][kk] = load_frag(E, tile_m0 + mrow0 + g * 16 + l, kk, q);

    if (tid < 128) { labC[tid] = labels[n_begin + tid]; colacc[tid] = 0.0f; }
    else           { labR[tid - 128] = labels[tile_m0 + (tid - 128)]; }
    __syncthreads();

    int lrow[8];
#pragma unroll
    for (int g = 0; g < 2; ++g)
#pragma unroll
        for (int rr = 0; rr < 4; ++rr)
            lrow[g * 4 + rr] = labR[mrow0 + g * 16 + q * 4 + rr];

    float sum[8];
#pragma unroll
    for (int i = 0; i < 8; ++i) sum[i] = 0.0f;

    // ---- compute: 8 subtiles of 16 cols; B frags converted from E ----
#pragma clang loop unroll(disable)
    for (int s = 0; s < 8; ++s) {
        const int brow = n_begin + s * 16 + l;
        bf16x8 b0 = load_frag(E, brow, 0, q);
        bf16x8 b1 = load_frag(E, brow, 1, q);
        bf16x8 b2 = load_frag(E, brow, 2, q);
        bf16x8 b3 = load_frag(E, brow, 3, q);
        const int lc = labC[s * 16 + l];

        f32x4 acc0 = (f32x4){0.f, 0.f, 0.f, 0.f};
        f32x4 acc1 = (f32x4){0.f, 0.f, 0.f, 0.f};
        acc0 = __builtin_amdgcn_mfma_f32_16x16x32_bf16(a[0][0], b0, acc0, 0, 0, 0);
        acc0 = __builtin_amdgcn_mfma_f32_16x16x32_bf16(a[0][1], b1, acc0, 0, 0, 0);
        acc0 = __builtin_amdgcn_mfma_f32_16x16x32_bf16(a[0][2], b2, acc0, 0, 0, 0);
        acc0 = __builtin_amdgcn_mfma_f32_16x16x32_bf16(a[0][3], b3, acc0, 0, 0, 0);
        acc1 = __builtin_amdgcn_mfma_f32_16x16x32_bf16(a[1][0], b0, acc1, 0, 0, 0);
        acc1 = __builtin_amdgcn_mfma_f32_16x16x32_bf16(a[1][1], b1, acc1, 0, 0, 0);
        acc1 = __builtin_amdgcn_mfma_f32_16x16x32_bf16(a[1][2], b2, acc1, 0, 0, 0);
        acc1 = __builtin_amdgcn_mfma_f32_16x16x32_bf16(a[1][3], b3, acc1, 0, 0, 0);

        float cp = 0.0f;
#pragma unroll
        for (int g = 0; g < 2; ++g) {
#pragma unroll
            for (int rr = 0; rr < 4; ++rr) {
                float sv = (g == 0) ? acc0[rr] : acc1[rr];
                bool eq = (lrow[g * 4 + rr] == lc);
                float cc = eq ? -LOG2E : LOG2E;
                float term = EXP2(cc * (sv - 0.1f));
                sum[g * 4 + rr] += term;
                cp += term;
            }
        }
        if (!diag) {
            cp += __shfl_xor(cp, 16);   // reduce over q-quarters
            cp += __shfl_xor(cp, 32);
            if (q == 0) atomicAdd(&colacc[s * 16 + l], cp);  // LDS only
        }
    }

    // Row credits: reduce across the 16 column-lanes, PLAIN stores, plane c.
#pragma unroll
    for (int i = 0; i < 8; ++i) {
        float v = sum[i];
        v += __shfl_xor(v, 1);
        v += __shfl_xor(v, 2);
        v += __shfl_xor(v, 4);
        v += __shfl_xor(v, 8);
        sum[i] = v;
    }
    if (l == 0) {
#pragma unroll
        for (int g = 0; g < 2; ++g)
#pragma unroll
            for (int rr = 0; rr < 4; ++rr)
                part[(size_t)c * N + tile_m0 + mrow0 + g * 16 + q * 4 + rr] = sum[g * 4 + rr];
    }

    // Col credits: PLAIN stores to plane r (off-diagonal only).
    __syncthreads();
    if (!diag && tid < 128)
        part[(size_t)r * N + n_begin + tid] = colacc[tid];
}

// Kernel 2: rowsum_i = sum over 64 planes; log; block-reduce; ticketed final.
__global__ void finalize_kernel(const float* __restrict__ part,
                                float* __restrict__ bpart,
                                unsigned int* __restrict__ counter,
                                float* __restrict__ out) {
    __shared__ float red[4];
    __shared__ unsigned int tk;
    const int tid = threadIdx.x;
    const int i = blockIdx.x * 256 + tid;

    float s = 0.0f;
#pragma unroll 8
    for (int x = 0; x < NPLANE; ++x) s += part[(size_t)x * N + i];
    float v = LOG2(s) * LN2;
#pragma unroll
    for (int off = 1; off <= 32; off <<= 1) v += __shfl_xor(v, off);
    if ((tid & 63) == 0) red[tid >> 6] = v;
    __syncthreads();
    if (tid == 0) {
        bpart[blockIdx.x] = red[0] + red[1] + red[2] + red[3];
        __threadfence();                       // release bpart store
        tk = atomicAdd(counter, 1u);
    }
    __syncthreads();
    if (tk == 31u) {                           // last block finalizes
        __threadfence();                       // acquire
        if (tid < 64) {
            float t = (tid < 32)
                ? __hip_atomic_load(&bpart[tid], __ATOMIC_RELAXED,
                                    __HIP_MEMORY_SCOPE_AGENT)
                : 0.0f;
#pragma unroll
            for (int off = 1; off <= 32; off <<= 1) t += __shfl_xor(t, off);
            if (tid == 0) out[0] = t * (1.0f / (float)N);
        }
    }
}

extern "C" void kernel_launch(void* const* d_in, const int* in_sizes, int n_in,
                              void* d_out, int out_size, void* d_ws, size_t ws_size,
                              hipStream_t stream) {
    const float* E = (const float*)d_in[0];
    const int* labels = (const int*)d_in[1];
    float* out = (float*)d_out;

    float* part = (float*)d_ws;                                 // 64*8192*4 = 2 MiB
    float* bpart = part + (size_t)NPLANE * N;                   // 32 floats
    unsigned int* counter = (unsigned int*)(bpart + 32);        // 4 B

    fused_kernel<<<2080, 256, 0, stream>>>(E, labels, part, counter);
    finalize_kernel<<<32, 256, 0, stream>>>(part, bpart, counter, out);
}

// Round 16
// 87.216 us; speedup vs baseline: 1.6314x; 1.6314x over previous
//
#include <hip/hip_runtime.h>
#include <hip/hip_bf16.h>

#define N 8192
#define D 128
#define LOG2E  1.44269504088896f
#define LN2    0.69314718055995f
#define NPLANE 64

typedef __attribute__((ext_vector_type(8))) short bf16x8;
typedef __attribute__((ext_vector_type(4))) float f32x4;

#if __has_builtin(__builtin_amdgcn_exp2f)
#define EXP2(x) __builtin_amdgcn_exp2f(x)
#else
#define EXP2(x) exp2f(x)
#endif
#if __has_builtin(__builtin_amdgcn_logf)
#define LOG2(x) __builtin_amdgcn_logf(x)
#else
#define LOG2(x) log2f(x)
#endif

static __device__ __forceinline__ unsigned short f2bf(float f) {
    union { float f; unsigned int u; } x;
    x.f = f;
    unsigned int r = ((x.u >> 16) & 1u) + 0x7FFFu;  // round-to-nearest-even
    return (unsigned short)((x.u + r) >> 16);
}

// Kernel 1 (R11): E (fp32) -> Eb2 (bf16) in FRAGMENT-MAJOR layout.
// Chunk (S,kk,lane) at byte S*4096 + kk*1024 + lane*16 -> every MFMA frag
// load is ONE contiguous 1-KB wave-load (zero amplification).
__global__ void prep_kernel(const float* __restrict__ E,
                            uint4* __restrict__ Eb2,
                            unsigned int* __restrict__ counter) {
    const int j = blockIdx.x * 256 + threadIdx.x;   // 0..131071
    const int l  = j & 15;
    const int q  = (j >> 4) & 3;
    const int kk = (j >> 6) & 3;
    const int S  = j >> 8;
    const float4* src = (const float4*)(E + (size_t)(S * 16 + l) * D + kk * 32 + q * 8);
    float4 f0 = src[0], f1 = src[1];
    uint4 o;
    o.x = f2bf(f0.x) | ((unsigned)f2bf(f0.y) << 16);
    o.y = f2bf(f0.z) | ((unsigned)f2bf(f0.w) << 16);
    o.z = f2bf(f1.x) | ((unsigned)f2bf(f1.y) << 16);
    o.w = f2bf(f1.z) | ((unsigned)f2bf(f1.w) << 16);
    Eb2[j] = o;
    if (j == 0) *counter = 0u;
}

// Kernel 2 (R16): R11 + B-TILE THROUGH LDS (B only — R10's A+B staging cost
// 2 blocks/CU; B-only is 32 KB -> 4 blocks/CU).
// R15's diagnostic: fused time tracks exposed global-load count in the
// subtile loop (VGPR-56 remat variant = 3x loads = 3x time). Fix: stage the
// whole 32-KB B tile in ONE burst of 8 independent coalesced wave-loads
// (single latency exposure, deep MLP), then the subtile loop has ZERO
// global loads — only ds_read_b128 (~12 cyc, pipelined, conflict-free:
// fragment-major is contiguous stride-16, no padding needed).
// Kept: fragment-major A direct loads (R11), triangular symmetry + plane
// stores / no global atomics (R9), rolled loops (R4), no min-waves (R2).
__global__ __launch_bounds__(256) void fused_kernel(
        const unsigned short* __restrict__ Eb2,
        const int* __restrict__ labels,
        float* __restrict__ part) {
    __shared__ __align__(16) char bB[32768];   // 8 subtile-chunks x 4096 B
    __shared__ int   labC[128];
    __shared__ int   labR[128];
    __shared__ float colacc[128];

    const int tid  = threadIdx.x;
    const int wid  = tid >> 6;     // 0..3
    const int lane = tid & 63;
    const int q = lane >> 4;       // 0..3
    const int l = lane & 15;       // 0..15

    // Triangular tile decode b -> (r, c), r <= c, 64 row-tiles (128 wide).
    const int b = blockIdx.x;
    int r = (int)(64.5f - sqrtf(64.5f * 64.5f - 2.0f * (float)b));
    while ((r + 1) * 64 - ((r + 1) * r) / 2 <= b) ++r;
    while (r * 64 - (r * (r - 1)) / 2 > b) --r;
    const int c = r + (b - (r * 64 - (r * (r - 1)) / 2));
    const bool diag = (r == c);
    const int tile_m0 = r * 128;
    const int n_begin = c * 128;
    const int mrow0 = wid * 32;            // wave's row strip within tile

    const char* base = (const char*)Eb2;

    // ---- one burst: stage 32-KB B tile (8 coalesced sweeps) + A frags ----
    const char* gB = base + (size_t)(c * 8) * 4096;
    float4 st[8];
#pragma unroll
    for (int i = 0; i < 8; ++i)
        st[i] = *(const float4*)(gB + i * 4096 + tid * 16);

    // A fragments: contiguous 1-KB wave-loads from fragment-major Eb2.
    bf16x8 a[2][4];
#pragma unroll
    for (int g = 0; g < 2; ++g) {
        const char* pa = base + (size_t)(r * 8 + wid * 2 + g) * 4096 + lane * 16;
#pragma unroll
        for (int kk = 0; kk < 4; ++kk)
            a[g][kk] = *(const bf16x8*)(pa + kk * 1024);
    }

#pragma unroll
    for (int i = 0; i < 8; ++i)
        *(float4*)(bB + i * 4096 + tid * 16) = st[i];

    if (tid < 128) { labC[tid] = labels[n_begin + tid]; colacc[tid] = 0.0f; }
    else           { labR[tid - 128] = labels[tile_m0 + (tid - 128)]; }
    __syncthreads();   // the ONLY barrier before compute

    int lrow[8];
#pragma unroll
    for (int g = 0; g < 2; ++g)
#pragma unroll
        for (int rr = 0; rr < 4; ++rr)
            lrow[g * 4 + rr] = labR[mrow0 + g * 16 + q * 4 + rr];

    float sum[8];
#pragma unroll
    for (int i = 0; i < 8; ++i) sum[i] = 0.0f;

    // ---- compute: 8 subtiles; B frags from LDS (zero global loads) ----
#pragma clang loop unroll(disable)
    for (int s = 0; s < 8; ++s) {
        const char* pb = bB + s * 4096 + lane * 16;
        bf16x8 b0 = *(const bf16x8*)(pb);
        bf16x8 b1 = *(const bf16x8*)(pb + 1024);
        bf16x8 b2 = *(const bf16x8*)(pb + 2048);
        bf16x8 b3 = *(const bf16x8*)(pb + 3072);
        const int lc = labC[s * 16 + l];

        f32x4 acc0 = (f32x4){0.f, 0.f, 0.f, 0.f};
        f32x4 acc1 = (f32x4){0.f, 0.f, 0.f, 0.f};
        acc0 = __builtin_amdgcn_mfma_f32_16x16x32_bf16(a[0][0], b0, acc0, 0, 0, 0);
        acc0 = __builtin_amdgcn_mfma_f32_16x16x32_bf16(a[0][1], b1, acc0, 0, 0, 0);
        acc0 = __builtin_amdgcn_mfma_f32_16x16x32_bf16(a[0][2], b2, acc0, 0, 0, 0);
        acc0 = __builtin_amdgcn_mfma_f32_16x16x32_bf16(a[0][3], b3, acc0, 0, 0, 0);
        acc1 = __builtin_amdgcn_mfma_f32_16x16x32_bf16(a[1][0], b0, acc1, 0, 0, 0);
        acc1 = __builtin_amdgcn_mfma_f32_16x16x32_bf16(a[1][1], b1, acc1, 0, 0, 0);
        acc1 = __builtin_amdgcn_mfma_f32_16x16x32_bf16(a[1][2], b2, acc1, 0, 0, 0);
        acc1 = __builtin_amdgcn_mfma_f32_16x16x32_bf16(a[1][3], b3, acc1, 0, 0, 0);

        float cp = 0.0f;
#pragma unroll
        for (int g = 0; g < 2; ++g) {
#pragma unroll
            for (int rr = 0; rr < 4; ++rr) {
                float sv = (g == 0) ? acc0[rr] : acc1[rr];
                bool eq = (lrow[g * 4 + rr] == lc);
                float cc = eq ? -LOG2E : LOG2E;
                float term = EXP2(cc * (sv - 0.1f));
                sum[g * 4 + rr] += term;
                cp += term;
            }
        }
        if (!diag) {
            cp += __shfl_xor(cp, 16);   // reduce over q-quarters
            cp += __shfl_xor(cp, 32);
            if (q == 0) atomicAdd(&colacc[s * 16 + l], cp);  // LDS only
        }
    }

    // Row credits: reduce across the 16 column-lanes, PLAIN stores, plane c.
#pragma unroll
    for (int i = 0; i < 8; ++i) {
        float v = sum[i];
        v += __shfl_xor(v, 1);
        v += __shfl_xor(v, 2);
        v += __shfl_xor(v, 4);
        v += __shfl_xor(v, 8);
        sum[i] = v;
    }
    if (l == 0) {
#pragma unroll
        for (int g = 0; g < 2; ++g)
#pragma unroll
            for (int rr = 0; rr < 4; ++rr)
                part[(size_t)c * N + tile_m0 + mrow0 + g * 16 + q * 4 + rr] = sum[g * 4 + rr];
    }

    // Col credits: PLAIN stores to plane r (off-diagonal only).
    __syncthreads();
    if (!diag && tid < 128)
        part[(size_t)r * N + n_begin + tid] = colacc[tid];
}

// Kernel 3: rowsum_i = sum over 64 planes; log; block-reduce; ticketed final.
__global__ void finalize_kernel(const float* __restrict__ part,
                                float* __restrict__ bpart,
                                unsigned int* __restrict__ counter,
                                float* __restrict__ out) {
    __shared__ float red[4];
    __shared__ unsigned int tk;
    const int tid = threadIdx.x;
    const int i = blockIdx.x * 256 + tid;

    float s = 0.0f;
#pragma unroll 8
    for (int x = 0; x < NPLANE; ++x) s += part[(size_t)x * N + i];
    float v = LOG2(s) * LN2;
#pragma unroll
    for (int off = 1; off <= 32; off <<= 1) v += __shfl_xor(v, off);
    if ((tid & 63) == 0) red[tid >> 6] = v;
    __syncthreads();
    if (tid == 0) {
        bpart[blockIdx.x] = red[0] + red[1] + red[2] + red[3];
        __threadfence();                       // release bpart store
        tk = atomicAdd(counter, 1u);
    }
    __syncthreads();
    if (tk == 31u) {                           // last block finalizes
        __threadfence();                       // acquire
        if (tid < 64) {
            float t = (tid < 32)
                ? __hip_atomic_load(&bpart[tid], __ATOMIC_RELAXED,
                                    __HIP_MEMORY_SCOPE_AGENT)
                : 0.0f;
#pragma unroll
            for (int off = 1; off <= 32; off <<= 1) t += __shfl_xor(t, off);
            if (tid == 0) out[0] = t * (1.0f / (float)N);
        }
    }
}

extern "C" void kernel_launch(void* const* d_in, const int* in_sizes, int n_in,
                              void* d_out, int out_size, void* d_ws, size_t ws_size,
                              hipStream_t stream) {
    const float* E = (const float*)d_in[0];
    const int* labels = (const int*)d_in[1];
    float* out = (float*)d_out;

    unsigned short* Eb2 = (unsigned short*)d_ws;                // 2 MiB, fragment-major
    float* part = (float*)((char*)d_ws + (size_t)N * D * 2);    // 64*8192*4 = 2 MiB
    float* bpart = part + (size_t)NPLANE * N;                   // 32 floats
    unsigned int* counter = (unsigned int*)(bpart + 32);        // 4 B

    prep_kernel<<<512, 256, 0, stream>>>(E, (uint4*)Eb2, counter);
    fused_kernel<<<2080, 256, 0, stream>>>(Eb2, labels, part);
    finalize_kernel<<<32, 256, 0, stream>>>(part, bpart, counter, out);
}